// Round 6
// baseline (232.052 us; speedup 1.0000x reference)
//
#include <hip/hip_runtime.h>

// EnvironmentalAugmentations: pink = AR(1) scan of white noise (a=0.99, b=0.01),
// mixed = waveform + 0.05*pink, out = mixed / max(|mixed|) if max > 1 else mixed.
// Shapes: (256 channels, 220500 samples), f32 in / f32 out.
//
// Chunked-independence: 0.99^1024 = 3.4e-5 -> each 8192-sample chunk computed
// independently with a 1024-sample warm-up (truncation error < 1e-6 in output).
// Entry-state trick: chunk 0 uses E = w[0]; exact because a + b = 1.
//
// R1 175us / R3 173us / R4 170us / R5(no atomic) 170us -> common floor is NOT
// the atomic. Measured: occ 40% (12.8 waves/CU), VGPR 52 -> compiler sank all
// loads to use-sites; avg in-flight/wave ~320B -> predicted 2.6 TB/s == measured
// 2.7 TB/s. Memory-parallelism bound.
// R6: force burst loads: launch_bounds(256,2) + asm liveness pins on all 17
// float4 loads so they issue back-to-back (17KB in flight per wave).

#define TLEN 220500
#define CHANNELS 256

constexpr int CL   = 8192;          // samples per block
constexpr int NT   = 256;           // threads per block
constexpr int NSB  = 8;             // superblocks per chunk (1024 samples each)
constexpr int NCHUNK = (TLEN + CL - 1) / CL;   // 27
constexpr int NBLK = NCHUNK * CHANNELS;        // 6912 pink_mix blocks

constexpr float AC = 0.99f;
constexpr float BC = 0.01f;
constexpr float NL = 0.05f;

constexpr double dpow(double a, int n) { double r = 1.0; for (int i = 0; i < n; ++i) r *= a; return r; }

// Geometric Hillis-Steele step multipliers, 4-sample granularity: 0.99^(4d)
constexpr float WP0 = (float)dpow(0.99, 4 * 1);
constexpr float WP1 = (float)dpow(0.99, 4 * 2);
constexpr float WP2 = (float)dpow(0.99, 4 * 4);
constexpr float WP3 = (float)dpow(0.99, 4 * 8);
constexpr float WP4 = (float)dpow(0.99, 4 * 16);
constexpr float WP5 = (float)dpow(0.99, 4 * 32);
constexpr float A256  = (float)dpow(0.99, 256);    // wave span (64 lanes x 4)
constexpr float A1024 = (float)dpow(0.99, 1024);   // superblock span
constexpr float L2A4   = -0.05799827878044602f;    // 4   * log2(0.99)
constexpr float L2A256 = -3.7118898419485456f;     // 256 * log2(0.99)

__global__ void init_max_kernel(unsigned int* gmax) { *gmax = 0u; }

__device__ __forceinline__ float wave_scan4(float f, int lane) {
    // inclusive geometric scan across 64 lanes, 4 samples per lane
    { float o = __shfl_up(f, 1,  64); if (lane >= 1)  f = fmaf(WP0, o, f); }
    { float o = __shfl_up(f, 2,  64); if (lane >= 2)  f = fmaf(WP1, o, f); }
    { float o = __shfl_up(f, 4,  64); if (lane >= 4)  f = fmaf(WP2, o, f); }
    { float o = __shfl_up(f, 8,  64); if (lane >= 8)  f = fmaf(WP3, o, f); }
    { float o = __shfl_up(f, 16, 64); if (lane >= 16) f = fmaf(WP4, o, f); }
    { float o = __shfl_up(f, 32, 64); if (lane >= 32) f = fmaf(WP5, o, f); }
    return f;
}

#define PIN4(v) asm volatile("" : "+v"((v).x), "+v"((v).y), "+v"((v).z), "+v"((v).w))

// USE_ATOMIC=1 is the fallback path (ws too small): old atomicMax into gmax.
template <int USE_ATOMIC>
__global__ __launch_bounds__(NT, 2)
void pink_mix_kernel(const float* __restrict__ waveform,
                     const float* __restrict__ white,
                     float* __restrict__ out,
                     unsigned int* __restrict__ gmax,
                     float* __restrict__ blockmax)
{
    __shared__ float sB[NSB + 1][4];   // wave totals: 8 main superblocks + warm-up
    __shared__ float sM[4];            // per-wave max
    __shared__ float sW0;              // first white sample of chunk

    const int chunk = blockIdx.x;
    const int ch    = blockIdx.y;
    const int c0    = chunk * CL;
    const size_t rowoff = (size_t)ch * TLEN;
    const float* __restrict__ wrow = white + rowoff;
    const float* __restrict__ arow = waveform + rowoff;
    float* __restrict__ orow = out + rowoff;

    const int tid  = threadIdx.x;
    const int lane = tid & 63;
    const int wv   = tid >> 6;

    // ---- BURST: issue all 17 coalesced float4 loads back-to-back, then pin
    //      them live so the compiler cannot sink them to use-sites. ----
    float4 wf[NSB];   // white
    float4 af[NSB];   // waveform
    #pragma unroll
    for (int i = 0; i < NSB; ++i) {
        int g = c0 + i * 1024 + 4 * tid;
        if (g < TLEN) {
            wf[i] = *reinterpret_cast<const float4*>(wrow + g);   // TLEN%4==0
            af[i] = *reinterpret_cast<const float4*>(arow + g);
        } else {
            wf[i] = make_float4(0.f, 0.f, 0.f, 0.f);
            af[i] = make_float4(0.f, 0.f, 0.f, 0.f);
        }
    }
    float4 wu = make_float4(0.f, 0.f, 0.f, 0.f);
    if (chunk > 0)
        wu = *reinterpret_cast<const float4*>(wrow + (c0 - 1024) + 4 * tid);
    #pragma unroll
    for (int i = 0; i < NSB; ++i) { PIN4(wf[i]); PIN4(af[i]); }
    PIN4(wu);

    // ---- per-superblock: 4-sample serial + wave scan; lane-excl kept in regs ----
    float eB[NSB];
    #pragma unroll
    for (int i = 0; i < NSB; ++i) {
        float f = BC * wf[i].x;
        f = fmaf(AC, f, BC * wf[i].y);
        f = fmaf(AC, f, BC * wf[i].z);
        f = fmaf(AC, f, BC * wf[i].w);
        float pB = wave_scan4(f, lane);
        float e  = __shfl_up(pB, 1, 64);
        eB[i] = (lane == 0) ? 0.f : e;
        if (lane == 63) sB[i][wv] = pB;
    }

    // ---- warm-up superblock [c0-1024, c0) ----
    if (chunk > 0) {
        float f = BC * wu.x;
        f = fmaf(AC, f, BC * wu.y);
        f = fmaf(AC, f, BC * wu.z);
        f = fmaf(AC, f, BC * wu.w);
        float pB = wave_scan4(f, lane);
        if (lane == 63) sB[NSB][wv] = pB;
    }
    if (tid == 0) sW0 = wf[0].x;
    __syncthreads();

    // ---- chunk entry state (chunk 0: E = w[0]; exact since a+b=1) ----
    float E;
    if (chunk > 0) {
        float t = sB[NSB][0];
        t = fmaf(A256, t, sB[NSB][1]);
        t = fmaf(A256, t, sB[NSB][2]);
        t = fmaf(A256, t, sB[NSB][3]);
        E = t;
    } else {
        E = sW0;
    }

    // per-thread decay factors
    const float D4L = __builtin_exp2f((float)lane * L2A4);   // 0.99^(4*lane)
    const float DW  = __builtin_exp2f((float)wv   * L2A256); // 0.99^(256*wv)

    // ---- per-superblock: entry state, rescan, fused mix + store + max ----
    float mx = 0.f;
    #pragma unroll
    for (int i = 0; i < NSB; ++i) {
        const float b0 = sB[i][0], b1 = sB[i][1], b2 = sB[i][2];
        // wave-exclusive prefix within superblock (uniform per wave)
        float wB = 0.f;
        if (wv > 0) wB = b0;
        if (wv > 1) wB = fmaf(A256, wB, b1);
        if (wv > 2) wB = fmaf(A256, wB, b2);
        // this thread's entry state
        float f = fmaf(D4L, fmaf(DW, E, wB), eB[i]);

        int g = c0 + i * 1024 + 4 * tid;
        if (g < TLEN) {
            float4 m;
            f = fmaf(AC, f, BC * wf[i].x); m.x = fmaf(NL, f, af[i].x);
            f = fmaf(AC, f, BC * wf[i].y); m.y = fmaf(NL, f, af[i].y);
            f = fmaf(AC, f, BC * wf[i].z); m.z = fmaf(NL, f, af[i].z);
            f = fmaf(AC, f, BC * wf[i].w); m.w = fmaf(NL, f, af[i].w);
            *reinterpret_cast<float4*>(orow + g) = m;
            mx = fmaxf(mx, fmaxf(fmaxf(fabsf(m.x), fabsf(m.y)),
                                 fmaxf(fabsf(m.z), fabsf(m.w))));
        }
        // advance superblock entry: E' = 0.99^1024 * E + T_i
        float t = b0;
        t = fmaf(A256, t, b1);
        t = fmaf(A256, t, b2);
        t = fmaf(A256, t, sB[i][3]);
        E = fmaf(A1024, E, t);
    }

    // ---- block max: plain store (no hot atomic) ----
    #pragma unroll
    for (int d = 32; d >= 1; d >>= 1)
        mx = fmaxf(mx, __shfl_xor(mx, d, 64));
    if (lane == 0) sM[wv] = mx;
    __syncthreads();
    if (tid == 0) {
        float m = fmaxf(fmaxf(sM[0], sM[1]), fmaxf(sM[2], sM[3]));
        if (USE_ATOMIC) {
            atomicMax(gmax, __float_as_uint(m));
        } else {
            blockmax[ch * NCHUNK + chunk] = m;
        }
    }
}

// single-block reduce: 6912 per-block maxima -> gmax (uint float-bits)
__global__ __launch_bounds__(256)
void reduce_max_kernel(const float* __restrict__ blockmax, unsigned int* __restrict__ gmax)
{
    __shared__ float sM[4];
    const int tid  = threadIdx.x;
    const int lane = tid & 63;
    const int wv   = tid >> 6;
    float mx = 0.f;
    for (int i = tid; i < NBLK; i += 256)
        mx = fmaxf(mx, blockmax[i]);
    #pragma unroll
    for (int d = 32; d >= 1; d >>= 1)
        mx = fmaxf(mx, __shfl_xor(mx, d, 64));
    if (lane == 0) sM[wv] = mx;
    __syncthreads();
    if (tid == 0)
        *gmax = __float_as_uint(fmaxf(fmaxf(sM[0], sM[1]), fmaxf(sM[2], sM[3])));
}

__global__ __launch_bounds__(256)
void scale_kernel(float* __restrict__ out, const unsigned int* __restrict__ gmax, int n4)
{
    const float m = __uint_as_float(*gmax);
    const float s = (m > 1.0f) ? (1.0f / m) : 1.0f;
    float4* p = reinterpret_cast<float4*>(out);
    int i = blockIdx.x * blockDim.x + threadIdx.x;
    const int stride = gridDim.x * blockDim.x;
    for (; i < n4; i += stride) {
        float4 v = p[i];
        v.x *= s; v.y *= s; v.z *= s; v.w *= s;
        p[i] = v;
    }
}

extern "C" void kernel_launch(void* const* d_in, const int* in_sizes, int n_in,
                              void* d_out, int out_size, void* d_ws, size_t ws_size,
                              hipStream_t stream)
{
    const float* waveform = (const float*)d_in[0];
    const float* white    = (const float*)d_in[1];
    float* out            = (float*)d_out;

    // ws layout: [0] uint gmax (256B reserved), then NBLK floats of block maxima
    unsigned int* gmax = (unsigned int*)d_ws;
    float* blockmax    = (float*)((char*)d_ws + 256);
    const bool ws_ok   = ws_size >= 256 + (size_t)NBLK * sizeof(float);

    dim3 grid(NCHUNK, CHANNELS);           // 27 x 256 blocks
    const int n4 = out_size / 4;           // 14,112,000 float4s

    if (ws_ok) {
        hipLaunchKernelGGL((pink_mix_kernel<0>), grid, dim3(NT), 0, stream,
                           waveform, white, out, gmax, blockmax);
        hipLaunchKernelGGL(reduce_max_kernel, dim3(1), dim3(256), 0, stream,
                           blockmax, gmax);
    } else {
        hipLaunchKernelGGL(init_max_kernel, dim3(1), dim3(1), 0, stream, gmax);
        hipLaunchKernelGGL((pink_mix_kernel<1>), grid, dim3(NT), 0, stream,
                           waveform, white, out, gmax, blockmax);
    }
    hipLaunchKernelGGL(scale_kernel, dim3(3072), dim3(256), 0, stream,
                       out, gmax, n4);
}